// Round 1
// baseline (656.246 us; speedup 1.0000x reference)
//
#include <hip/hip_runtime.h>

// Problem: N=2048, F=64, S=512, D=512
//   gi[n,f,g] = sum_s x[n,f,s] * W_ih[f,g,s]   (+ b_ih)
//   r = sig(gi_r + b_hr); z = sig(gi_z + b_hz); n = tanh(gi_n + r*b_hn)
//   h = (1-z)*n                      out shape (N,F,D) fp32
//
// One block: one f, 128 x-rows x 64 d-cols, all 3 gates fused.
// bf16 MFMA 16x16x32, fp32 accum. Reg-staged LDS with XOR swizzle (T2).

#define NN 2048
#define FF 64
#define SS 512
#define DD 512

#define BM 128
#define BD 64
#define BK 64
#define NKT (SS / BK)  // 8

typedef float f32x4 __attribute__((ext_vector_type(4)));
typedef __bf16 bf16x8 __attribute__((ext_vector_type(8)));
typedef unsigned short ushort8 __attribute__((ext_vector_type(8)));
typedef unsigned int uint32x4 __attribute__((ext_vector_type(4)));

__device__ __forceinline__ ushort8 cvt8(const f32x4 a, const f32x4 b) {
    ushort8 r;
    r[0] = __builtin_bit_cast(unsigned short, (__bf16)a[0]);
    r[1] = __builtin_bit_cast(unsigned short, (__bf16)a[1]);
    r[2] = __builtin_bit_cast(unsigned short, (__bf16)a[2]);
    r[3] = __builtin_bit_cast(unsigned short, (__bf16)a[3]);
    r[4] = __builtin_bit_cast(unsigned short, (__bf16)b[0]);
    r[5] = __builtin_bit_cast(unsigned short, (__bf16)b[1]);
    r[6] = __builtin_bit_cast(unsigned short, (__bf16)b[2]);
    r[7] = __builtin_bit_cast(unsigned short, (__bf16)b[3]);
    return r;
}

extern "C" __global__ __launch_bounds__(256, 2)
void gru_fused(const float* __restrict__ x, const float* __restrict__ W,
               const float* __restrict__ b_ih, const float* __restrict__ b_hh,
               float* __restrict__ out)
{
    // LDS: A tile [128][64] bf16 (16 KB) at 0; B tile [3][64][64] bf16 (24 KB) at 16384
    __shared__ __align__(16) unsigned char lds[40960];

    const int t     = threadIdx.x;
    const int lane  = t & 63;
    const int wid   = t >> 6;      // 0..3
    const int wm    = wid >> 1;    // M half (0/1)
    const int wd    = wid & 1;     // D half (0/1)
    const int lrow  = lane & 15;
    const int khalf = lane >> 4;   // 0..3

    const int tile = blockIdx.x;   // 0..127, d-tile innermost
    const int f    = blockIdx.y;   // 0..63
    const int n0   = (tile >> 3) * BM;
    const int d0   = (tile & 7) * BD;

    // ---- staging coords: each thread owns 8-float segments ----
    const int colSeg = t & 7;      // *8 floats within the 64-wide K slab
    const int rBase  = t >> 3;     // 0..31

    const float* aPtr[4];
    int aOff[4];
#pragma unroll
    for (int p = 0; p < 4; ++p) {
        int row = rBase + 32 * p;                       // 0..127
        aPtr[p] = x + ((long)(n0 + row) * FF + f) * SS + colSeg * 8;
        aOff[p] = row * 128 + ((colSeg * 16) ^ ((row & 7) << 4));
    }
    const float* bPtr[6];
    int bOff[6];
#pragma unroll
    for (int p = 0; p < 6; ++p) {
        int ra   = rBase + 32 * p;                      // 0..191
        int gate = ra >> 6;                             // 0..2
        int dr   = ra & 63;
        bPtr[p] = W + ((long)f * (3 * DD) + gate * DD + d0 + dr) * SS + colSeg * 8;
        bOff[p] = 16384 + gate * 8192 + dr * 128 + ((colSeg * 16) ^ ((dr & 7) << 4));
    }

    f32x4 acc[3][4][2];
#pragma unroll
    for (int g = 0; g < 3; ++g)
#pragma unroll
        for (int i = 0; i < 4; ++i)
#pragma unroll
            for (int j = 0; j < 2; ++j)
                acc[g][i][j] = (f32x4){0.f, 0.f, 0.f, 0.f};

    // ---- prologue: load K-tile 0 into regs ----
    f32x4 va[4][2], vb[6][2];
#pragma unroll
    for (int p = 0; p < 4; ++p) {
        const f32x4* g = (const f32x4*)aPtr[p];
        va[p][0] = g[0]; va[p][1] = g[1];
    }
#pragma unroll
    for (int p = 0; p < 6; ++p) {
        const f32x4* g = (const f32x4*)bPtr[p];
        vb[p][0] = g[0]; vb[p][1] = g[1];
    }

    for (int kt = 0; kt < NKT; ++kt) {
        __syncthreads();  // previous iteration's ds_reads complete
#pragma unroll
        for (int p = 0; p < 4; ++p)
            *(ushort8*)(lds + aOff[p]) = cvt8(va[p][0], va[p][1]);
#pragma unroll
        for (int p = 0; p < 6; ++p)
            *(ushort8*)(lds + bOff[p]) = cvt8(vb[p][0], vb[p][1]);
        __syncthreads();

        // issue next tile's global loads early (hide HBM under MFMA)
        if (kt + 1 < NKT) {
            const long koff = (long)(kt + 1) * BK;
#pragma unroll
            for (int p = 0; p < 4; ++p) {
                const f32x4* g = (const f32x4*)(aPtr[p] + koff);
                va[p][0] = g[0]; va[p][1] = g[1];
            }
#pragma unroll
            for (int p = 0; p < 6; ++p) {
                const f32x4* g = (const f32x4*)(bPtr[p] + koff);
                vb[p][0] = g[0]; vb[p][1] = g[1];
            }
        }

#pragma unroll
        for (int kb = 0; kb < 2; ++kb) {
            bf16x8 af[4];
#pragma unroll
            for (int i = 0; i < 4; ++i) {
                int row = wm * 64 + i * 16 + lrow;
                int off = row * 128 + ((kb * 64 + khalf * 16) ^ ((row & 7) << 4));
                af[i] = __builtin_bit_cast(bf16x8, *(const uint32x4*)(lds + off));
            }
            bf16x8 bfr[3][2];
#pragma unroll
            for (int g = 0; g < 3; ++g)
#pragma unroll
                for (int j = 0; j < 2; ++j) {
                    int dr  = wd * 32 + j * 16 + lrow;
                    int off = 16384 + g * 8192 + dr * 128 +
                              ((kb * 64 + khalf * 16) ^ ((dr & 7) << 4));
                    bfr[g][j] = __builtin_bit_cast(bf16x8, *(const uint32x4*)(lds + off));
                }
#pragma unroll
            for (int g = 0; g < 3; ++g)
#pragma unroll
                for (int i = 0; i < 4; ++i)
#pragma unroll
                    for (int j = 0; j < 2; ++j)
                        acc[g][i][j] = __builtin_amdgcn_mfma_f32_16x16x32_bf16(
                            af[i], bfr[g][j], acc[g][i][j], 0, 0, 0);
        }
    }

    // ---- fused gate epilogue ----
    const long bBase = (long)f * (3 * DD);
#pragma unroll
    for (int j = 0; j < 2; ++j) {
        int d = d0 + wd * 32 + j * 16 + lrow;
        float bihr = b_ih[bBase + d];
        float bihz = b_ih[bBase + DD + d];
        float bihn = b_ih[bBase + 2 * DD + d];
        float bhr  = b_hh[bBase + d];
        float bhz  = b_hh[bBase + DD + d];
        float bhn  = b_hh[bBase + 2 * DD + d];
#pragma unroll
        for (int i = 0; i < 4; ++i) {
#pragma unroll
            for (int q = 0; q < 4; ++q) {
                int row = wm * 64 + i * 16 + khalf * 4 + q;
                float gr = acc[0][i][j][q] + bihr + bhr;
                float gz = acc[1][i][j][q] + bihz + bhz;
                float gy = acc[2][i][j][q] + bihn;
                float r  = 1.0f / (1.0f + __expf(-gr));
                float z  = 1.0f / (1.0f + __expf(-gz));
                float nv = tanhf(gy + r * bhn);
                long oi  = ((long)(n0 + row) * FF + f) * DD + d;
                out[oi]  = (1.0f - z) * nv;
            }
        }
    }
}

extern "C" void kernel_launch(void* const* d_in, const int* in_sizes, int n_in,
                              void* d_out, int out_size, void* d_ws, size_t ws_size,
                              hipStream_t stream) {
    const float* x   = (const float*)d_in[0];
    const float* W   = (const float*)d_in[1];
    const float* bih = (const float*)d_in[2];
    const float* bhh = (const float*)d_in[3];
    float* out       = (float*)d_out;

    dim3 grid(128, 64);   // (16 m-tiles x 8 d-tiles, d innermost), f
    dim3 block(256);
    gru_fused<<<grid, block, 0, stream>>>(x, W, bih, bhh, out);
}